// Round 4
// baseline (590.635 us; speedup 1.0000x reference)
//
#include <hip/hip_runtime.h>
#include <cstdint>
#include <cstddef>

// GCN: N=512, B=64, F=O=128, E=3, 2 layers. fp32 in memory, bf16 MFMA compute.
//
// This revision: NO LDS, NO barriers in the GEMM kernels. With K=128 every
// operand is loaded straight from global in MFMA fragment layout
// (row = lane&15, k-octet = (lane>>4)*8): wt/sup are bf16 k-contiguous
// (16B/lane), x/adj are fp32 k-contiguous (32B/lane + inline RNE cvt).
// L1 absorbs intra-block operand reuse; compiler pipelines loads vs MFMA
// with per-register vmcnt — no block-wide vmcnt(0)+barrier drain at all.
//
//   k_prep    : 8 blocks, weights -> wt bf16 [layer][4][o][f] (g=0..2 W[e]^T, 3 Wh^T)
//   k_support : grid (4,64); sup[e,b,o,n]=bf16(W^T X^T + b); tg = sigmoid(X Wh + bh)
//   k_agg     : grid (16,64); out = relu(sum_e adj[e,b,m,:] sup[e,b,:,:]^T)*t + x*(1-t)
// Layer-1 h lives in d_out; layer 2 runs in-place on d_out.

typedef __bf16 bf16x8 __attribute__((ext_vector_type(8)));
typedef float f32x4 __attribute__((ext_vector_type(4)));
typedef unsigned short u16x8 __attribute__((ext_vector_type(8)));

#define MFMA16(a, b, c) __builtin_amdgcn_mfma_f32_16x16x32_bf16((a), (b), (c), 0, 0, 0)

__device__ __forceinline__ unsigned short f2bf(float f) {  // RNE
  union { float f; unsigned int i; } v;
  v.f = f;
  return (unsigned short)((v.i + 0x7FFFu + ((v.i >> 16) & 1u)) >> 16);
}

// Load 8 consecutive fp32, convert to a bf16x8 fragment (32B/lane, aligned).
__device__ __forceinline__ bf16x8 ld8(const float* __restrict__ p) {
  float4 v0 = *(const float4*)p;
  float4 v1 = *(const float4*)(p + 4);
  union { u16x8 u; bf16x8 h; } c;
  c.u = (u16x8){ f2bf(v0.x), f2bf(v0.y), f2bf(v0.z), f2bf(v0.w),
                 f2bf(v1.x), f2bf(v1.y), f2bf(v1.z), f2bf(v1.w) };
  return c.h;
}

// ---------------------------------------------------------------------------
// k_prep: 8 blocks, each transposes one 128x128 weight matrix fp32->bf16 [o][f].
// ---------------------------------------------------------------------------
__global__ __launch_bounds__(256) void k_prep(
    const float* __restrict__ W1, const float* __restrict__ Wh1,
    const float* __restrict__ W2, const float* __restrict__ Wh2,
    unsigned short* __restrict__ wt) {
  __shared__ unsigned short T[128 * 136];
  const int tid = threadIdx.x;
  const int layer = blockIdx.x >> 2, g = blockIdx.x & 3;
  const float* src = (g < 3) ? ((layer ? W2 : W1) + g * 16384)
                             : (layer ? Wh2 : Wh1);
  unsigned short* dst = wt + layer * 65536 + g * 16384;
#pragma unroll
  for (int i = 0; i < 16; ++i) {
    int c = i * 256 + tid, f = c >> 5, p = (c & 31) * 4;
    float4 v = *(const float4*)(src + f * 128 + p);
    T[(p + 0) * 136 + f] = f2bf(v.x);
    T[(p + 1) * 136 + f] = f2bf(v.y);
    T[(p + 2) * 136 + f] = f2bf(v.z);
    T[(p + 3) * 136 + f] = f2bf(v.w);
  }
  __syncthreads();
#pragma unroll
  for (int i = 0; i < 8; ++i) {
    int c = i * 256 + tid, o = c >> 4, p = (c & 15) * 8;
    *(uint4*)(dst + o * 128 + p) = *(const uint4*)(&T[o * 136 + p]);
  }
}

// ---------------------------------------------------------------------------
// k_support: grid (4,64) = (n-tile 128, b), 4 waves, 2x2 wave tile of 64x64.
// g<3 : D[o,n] = W[g]^T @ X^T -> sup bf16 (+bias)
// g==3: D[n,o] = X @ Wh       -> tg fp32 sigmoid
// All fragments direct from global (wt bf16 16B/lane; x fp32 32B/lane + cvt).
// No LDS, no barriers.
// ---------------------------------------------------------------------------
__global__ __launch_bounds__(256) void k_support(
    const float* __restrict__ x, const unsigned short* __restrict__ wt,
    const float* __restrict__ bias, const float* __restrict__ bh,
    unsigned short* __restrict__ sup, float* __restrict__ tg) {
  const int tid = threadIdx.x, lane = tid & 63, wv = tid >> 6;
  const int wm = wv >> 1, wn = wv & 1;
  const int l15 = lane & 15, q = lane >> 4;
  const int b = blockIdx.y, n0 = blockIdx.x * 128;

  for (int g = 0; g < 4; ++g) {
    const unsigned short* wg = wt + g * 16384;
    f32x4 acc[4][4];
#pragma unroll
    for (int i = 0; i < 4; ++i)
#pragma unroll
      for (int j = 0; j < 4; ++j) acc[i][j] = (f32x4){0.f, 0.f, 0.f, 0.f};

    if (g < 3) {
#pragma unroll
      for (int kt = 0; kt < 4; ++kt) {
        const int kf = kt * 32 + q * 8;
        bf16x8 a[4], bb[4];
#pragma unroll
        for (int mt = 0; mt < 4; ++mt)
          a[mt] = *(const bf16x8*)(wg + (wm * 64 + mt * 16 + l15) * 128 + kf);
#pragma unroll
        for (int nt = 0; nt < 4; ++nt)
          bb[nt] = ld8(x + (size_t)(n0 + wn * 64 + nt * 16 + l15) * 8192 + b * 128 + kf);
#pragma unroll
        for (int mt = 0; mt < 4; ++mt)
#pragma unroll
          for (int nt = 0; nt < 4; ++nt)
            acc[mt][nt] = MFMA16(a[mt], bb[nt], acc[mt][nt]);
      }
      // sup[e,b,o,n] bf16: C row = o (q*4+r), col = n (l15)
      const size_t sb = (size_t)(g * 64 + b) * 65536;
#pragma unroll
      for (int mt = 0; mt < 4; ++mt) {
        int o = wm * 64 + mt * 16 + q * 4;
#pragma unroll
        for (int nt = 0; nt < 4; ++nt) {
          int nn = n0 + wn * 64 + nt * 16 + l15;
#pragma unroll
          for (int r = 0; r < 4; ++r) {
            float v = acc[mt][nt][r] + bias[g * 128 + o + r];
            sup[sb + (size_t)(o + r) * 512 + nn] = f2bf(v);
          }
        }
      }
    } else {
#pragma unroll
      for (int kt = 0; kt < 4; ++kt) {
        const int kf = kt * 32 + q * 8;
        bf16x8 a[4], bb[4];
#pragma unroll
        for (int mt = 0; mt < 4; ++mt)
          a[mt] = ld8(x + (size_t)(n0 + wm * 64 + mt * 16 + l15) * 8192 + b * 128 + kf);
#pragma unroll
        for (int nt = 0; nt < 4; ++nt)
          bb[nt] = *(const bf16x8*)(wg + (wn * 64 + nt * 16 + l15) * 128 + kf);
#pragma unroll
        for (int mt = 0; mt < 4; ++mt)
#pragma unroll
          for (int nt = 0; nt < 4; ++nt)
            acc[mt][nt] = MFMA16(a[mt], bb[nt], acc[mt][nt]);
      }
      // tg[n,b,o] fp32: C row = n (q*4+r), col = o (l15)
#pragma unroll
      for (int mt = 0; mt < 4; ++mt) {
#pragma unroll
        for (int nt = 0; nt < 4; ++nt) {
          int o = wn * 64 + nt * 16 + l15;
#pragma unroll
          for (int r = 0; r < 4; ++r) {
            int nn = n0 + wm * 64 + mt * 16 + q * 4 + r;
            float v = acc[mt][nt][r] + bh[o];
            tg[((size_t)nn * 64 + b) * 128 + o] = 1.f / (1.f + __expf(-v));
          }
        }
      }
    }
  }
}

// ---------------------------------------------------------------------------
// k_agg: grid (16,64) = (m-tile 32, b); 4 waves: (wv&1) -> m 16-row group,
// (wv>>1) -> o half (64). acc = 4 frags. A = adj fp32 rows (32B/lane + cvt),
// B = sup bf16 rows (16B/lane). No LDS, no barriers; 4 blocks/CU, 16 waves/CU.
// ---------------------------------------------------------------------------
__global__ __launch_bounds__(256) void k_agg(
    const float* __restrict__ adj, const unsigned short* __restrict__ sup,
    const float* __restrict__ tg, const float* __restrict__ x,
    float* __restrict__ dst) {
  const int tid = threadIdx.x, lane = tid & 63, wv = tid >> 6;
  const int l15 = lane & 15, q = lane >> 4;
  const int b = blockIdx.y, m0 = blockIdx.x * 32;
  const int ms = (wv & 1) * 16;      // m 16-row group within tile
  const int oh = (wv >> 1) * 64;     // o half

  f32x4 acc[4];
#pragma unroll
  for (int i = 0; i < 4; ++i) acc[i] = (f32x4){0.f, 0.f, 0.f, 0.f};

  for (int e = 0; e < 3; ++e) {
    const float* ap = adj + ((size_t)(e * 64 + b) * 512 + m0 + ms + l15) * 512 + q * 8;
    const unsigned short* sp =
        sup + (size_t)(e * 64 + b) * 65536 + (size_t)(oh + l15) * 512 + q * 8;
#pragma unroll 4
    for (int k32 = 0; k32 < 16; ++k32) {
      bf16x8 a = ld8(ap + k32 * 32);
#pragma unroll
      for (int ot = 0; ot < 4; ++ot) {
        bf16x8 bb = *(const bf16x8*)(sp + ot * 16 * 512 + k32 * 32);
        acc[ot] = MFMA16(a, bb, acc[ot]);
      }
    }
  }

  // Epilogue: relu + highway. C row = m (q*4+r), col = o (l15).
#pragma unroll
  for (int ot = 0; ot < 4; ++ot) {
#pragma unroll
    for (int r = 0; r < 4; ++r) {
      int m = m0 + ms + q * 4 + r;
      int o = oh + ot * 16 + l15;
      size_t ridx = (size_t)(m * 64 + b) * 128 + o;
      float agg = acc[ot][r];
      agg = agg > 0.f ? agg : 0.f;
      float tv = tg[ridx];
      float xv = x[ridx];
      dst[ridx] = fmaf(agg, tv, xv * (1.f - tv));
    }
  }
}

// ---------------------------------------------------------------------------
extern "C" void kernel_launch(void* const* d_in, const int* in_sizes, int n_in,
                              void* d_out, int out_size, void* d_ws, size_t ws_size,
                              hipStream_t stream) {
  const float* x   = (const float*)d_in[0];
  const float* adj = (const float*)d_in[1];
  const float* W1  = (const float*)d_in[2];
  const float* b1  = (const float*)d_in[3];
  const float* Wh1 = (const float*)d_in[4];
  const float* bh1 = (const float*)d_in[5];
  const float* W2  = (const float*)d_in[6];
  const float* b2  = (const float*)d_in[7];
  const float* Wh2 = (const float*)d_in[8];
  const float* bh2 = (const float*)d_in[9];
  float* out = (float*)d_out;

  char* ws = (char*)d_ws;
  unsigned short* sup = (unsigned short*)ws;              // 25,165,824 B
  float*          tg  = (float*)(ws + 25165824);          // 16,777,216 B
  unsigned short* wt  = (unsigned short*)(ws + 41943040); //    262,144 B

  dim3 blk(256);

  k_prep<<<dim3(8), blk, 0, stream>>>(W1, Wh1, W2, Wh2, wt);

  // Layer 1 (h -> d_out)
  k_support<<<dim3(4, 64), blk, 0, stream>>>(x, wt, b1, bh1, sup, tg);
  k_agg<<<dim3(16, 64), blk, 0, stream>>>(adj, sup, tg, x, out);

  // Layer 2 (in-place on d_out)
  k_support<<<dim3(4, 64), blk, 0, stream>>>(out, wt + 65536, b2, bh2, sup, tg);
  k_agg<<<dim3(16, 64), blk, 0, stream>>>(adj, sup, tg, out, out);
}

// Round 5
// 413.964 us; speedup vs baseline: 1.4268x; 1.4268x over previous
//
#include <hip/hip_runtime.h>
#include <cstdint>
#include <cstddef>

// GCN: N=512, B=64, F=O=128, E=3, 2 layers. fp32 in memory, bf16 MFMA compute.
//
// m97-style cooperative staging: global_load_lds (16B) into UNPADDED LDS with
// XOR-swizzled 16B chunks (pos = chunk ^ (row&7)) -> conflict-free ds_read_b128
// fragments (8 positions x 2 lanes = free 2-way).
//
//   k_prep     : 8 blocks; weights -> wt bf16 [layer][4][o][f] (g<3: W[e]^T, 3: Wh^T)
//   k_support  : grid (8,64) = (n-tile 64, b); sup[e,b,o,n] = bf16(W^T X^T + bias),
//                tg[n,b,o] = sigmoid(X Wh + bh). LDS-staged, padded rows (manual).
//   k_agg<L>   : grid (8,64) = (m-tile 64, b); out = relu(sum adj.sup^T)*t + x*(1-t)
//                L=1: A from fp32 adj (manual cvt stage) + writes adjb bf16
//                L=2: A from adjb via global_load_lds (L3-resident)
// Layer-1 h lives in d_out; layer 2 in-place on d_out.

typedef __bf16 bf16x8 __attribute__((ext_vector_type(8)));
typedef float f32x4 __attribute__((ext_vector_type(4)));
typedef unsigned short u16x8 __attribute__((ext_vector_type(8)));

#define MFMA16(a, b, c) __builtin_amdgcn_mfma_f32_16x16x32_bf16((a), (b), (c), 0, 0, 0)

__device__ __forceinline__ unsigned short f2bf(float f) {  // RNE
  union { float f; unsigned int i; } v;
  v.f = f;
  return (unsigned short)((v.i + 0x7FFFu + ((v.i >> 16) & 1u)) >> 16);
}

__device__ __forceinline__ u16x8 cvt8(float4 v0, float4 v1) {
  return (u16x8){ f2bf(v0.x), f2bf(v0.y), f2bf(v0.z), f2bf(v0.w),
                  f2bf(v1.x), f2bf(v1.y), f2bf(v1.z), f2bf(v1.w) };
}

// async global->LDS, 16B per lane; lds dest = wave-uniform base + lane*16
__device__ __forceinline__ void gl_lds16(const void* g, void* l) {
  __builtin_amdgcn_global_load_lds(
      (__attribute__((address_space(1))) void*)(g),
      (__attribute__((address_space(3))) void*)(l), 16, 0, 0);
}

// ---------------------------------------------------------------------------
// k_prep: 8 blocks; each transposes one 128x128 weight fp32 -> bf16 [o][f].
// ---------------------------------------------------------------------------
__global__ __launch_bounds__(256) void k_prep(
    const float* __restrict__ W1, const float* __restrict__ Wh1,
    const float* __restrict__ W2, const float* __restrict__ Wh2,
    unsigned short* __restrict__ wt) {
  __shared__ unsigned short T[128 * 136];
  const int tid = threadIdx.x;
  const int layer = blockIdx.x >> 2, g = blockIdx.x & 3;
  const float* src = (g < 3) ? ((layer ? W2 : W1) + g * 16384)
                             : (layer ? Wh2 : Wh1);
  unsigned short* dst = wt + layer * 65536 + g * 16384;
#pragma unroll
  for (int i = 0; i < 16; ++i) {
    int c = i * 256 + tid, f = c >> 5, p = (c & 31) * 4;
    float4 v = *(const float4*)(src + f * 128 + p);
    T[(p + 0) * 136 + f] = f2bf(v.x);
    T[(p + 1) * 136 + f] = f2bf(v.y);
    T[(p + 2) * 136 + f] = f2bf(v.z);
    T[(p + 3) * 136 + f] = f2bf(v.w);
  }
  __syncthreads();
#pragma unroll
  for (int i = 0; i < 8; ++i) {
    int c = i * 256 + tid, o = c >> 4, p = (c & 15) * 8;
    *(uint4*)(dst + o * 128 + p) = *(const uint4*)(&T[o * 136 + p]);
  }
}

// ---------------------------------------------------------------------------
// k_support: grid (8,64) = (n-tile 64, b). 4 waves. LDS ~52KB -> 3 blocks/CU.
// g<3 : D[o,n] = W[g]^T @ X^T -> sup bf16 (+bias)     (M=o 128, N=n 64)
// g==3: D[n,o] = X @ Wh       -> tg fp32 sigmoid      (M=n 64, O=o 128)
// ---------------------------------------------------------------------------
__global__ __launch_bounds__(256) void k_support(
    const float* __restrict__ x, const unsigned short* __restrict__ wt,
    const float* __restrict__ bias, const float* __restrict__ bh,
    unsigned short* __restrict__ sup, float* __restrict__ tg) {
  __shared__ __align__(16) unsigned short Xs[64 * 136];   // [n][f] bf16, padded
  __shared__ __align__(16) unsigned short Ws[128 * 136];  // [o][f] bf16, padded
  const int tid = threadIdx.x, lane = tid & 63, wv = tid >> 6;
  const int l15 = lane & 15, q = lane >> 4;
  const int b = blockIdx.y, n0 = blockIdx.x * 64;

  // stage Xs: 64 n-rows x 128 f (fp32 -> bf16)
#pragma unroll
  for (int is = 0; is < 8; ++is) {
    int flat = is * 256 + tid;  // 0..2047
    int row = flat >> 5, c4 = (flat & 31) * 4;
    float4 v = *(const float4*)(x + (size_t)(n0 + row) * 8192 + b * 128 + c4);
    ushort4 u = { f2bf(v.x), f2bf(v.y), f2bf(v.z), f2bf(v.w) };
    *(ushort4*)(&Xs[row * 136 + c4]) = u;
  }

  for (int g = 0; g < 4; ++g) {
    __syncthreads();  // Ws overwrite vs previous g's reads (also fences Xs at g=0)
#pragma unroll
    for (int is = 0; is < 8; ++is) {
      int flat = is * 256 + tid;  // 0..2047
      int row = flat >> 4, c8 = (flat & 15) * 8;
      *(uint4*)(&Ws[row * 136 + c8]) =
          *(const uint4*)(wt + g * 16384 + row * 128 + c8);
    }
    __syncthreads();

    if (g < 3) {
      f32x4 acc[4][2];
#pragma unroll
      for (int i = 0; i < 4; ++i)
#pragma unroll
        for (int j = 0; j < 2; ++j) acc[i][j] = (f32x4){0.f, 0.f, 0.f, 0.f};
#pragma unroll
      for (int kt = 0; kt < 4; ++kt) {
        int kf = kt * 32 + q * 8;
        bf16x8 a[4], bb[2];
#pragma unroll
        for (int mt = 0; mt < 4; ++mt)
          a[mt] = *(const bf16x8*)(&Ws[((wv >> 1) * 64 + mt * 16 + l15) * 136 + kf]);
#pragma unroll
        for (int nt = 0; nt < 2; ++nt)
          bb[nt] = *(const bf16x8*)(&Xs[((wv & 1) * 32 + nt * 16 + l15) * 136 + kf]);
#pragma unroll
        for (int mt = 0; mt < 4; ++mt)
#pragma unroll
          for (int nt = 0; nt < 2; ++nt)
            acc[mt][nt] = MFMA16(a[mt], bb[nt], acc[mt][nt]);
      }
      const size_t sb = (size_t)(g * 64 + b) * 65536;
#pragma unroll
      for (int mt = 0; mt < 4; ++mt) {
#pragma unroll
        for (int nt = 0; nt < 2; ++nt) {
          int nn = n0 + (wv & 1) * 32 + nt * 16 + l15;
#pragma unroll
          for (int r = 0; r < 4; ++r) {
            int o = (wv >> 1) * 64 + mt * 16 + q * 4 + r;
            float v = acc[mt][nt][r] + bias[g * 128 + o];
            sup[sb + (size_t)o * 512 + nn] = f2bf(v);
          }
        }
      }
    } else {
      f32x4 acc[2][4];
#pragma unroll
      for (int i = 0; i < 2; ++i)
#pragma unroll
        for (int j = 0; j < 4; ++j) acc[i][j] = (f32x4){0.f, 0.f, 0.f, 0.f};
#pragma unroll
      for (int kt = 0; kt < 4; ++kt) {
        int kf = kt * 32 + q * 8;
        bf16x8 a[2], bb[4];
#pragma unroll
        for (int mt = 0; mt < 2; ++mt)
          a[mt] = *(const bf16x8*)(&Xs[((wv >> 1) * 32 + mt * 16 + l15) * 136 + kf]);
#pragma unroll
        for (int nt = 0; nt < 4; ++nt)
          bb[nt] = *(const bf16x8*)(&Ws[((wv & 1) * 64 + nt * 16 + l15) * 136 + kf]);
#pragma unroll
        for (int mt = 0; mt < 2; ++mt)
#pragma unroll
          for (int nt = 0; nt < 4; ++nt)
            acc[mt][nt] = MFMA16(a[mt], bb[nt], acc[mt][nt]);
      }
#pragma unroll
      for (int mt = 0; mt < 2; ++mt) {
#pragma unroll
        for (int nt = 0; nt < 4; ++nt) {
          int o = (wv & 1) * 64 + nt * 16 + l15;
#pragma unroll
          for (int r = 0; r < 4; ++r) {
            int nn = n0 + (wv >> 1) * 32 + mt * 16 + q * 4 + r;
            float v = acc[mt][nt][r] + bh[o];
            tg[((size_t)nn * 64 + b) * 128 + o] = 1.f / (1.f + __expf(-v));
          }
        }
      }
    }
  }
}

// ---------------------------------------------------------------------------
// k_agg<LAYER>: grid (8,64) = (m-tile 64, b). Block tile 64m x 128o, K=3e*512n
// in 24 chunks of 64. LDS: As 8KB + Bs 16KB, XOR-swizzled 16B chunks.
// Waves: wm=wv>>1 (m 32-half), wn=wv&1 (o 64-half); acc 2x4 frags.
// ---------------------------------------------------------------------------
template <int LAYER>
__global__ __launch_bounds__(256) void k_agg(
    const float* __restrict__ adjf, unsigned short* __restrict__ adjb,
    const unsigned short* __restrict__ sup, const float* __restrict__ tg,
    const float* __restrict__ x, float* __restrict__ dst) {
  __shared__ __align__(16) unsigned short As[64 * 64];    // [m][n64] swizzled
  __shared__ __align__(16) unsigned short Bs[128 * 64];   // [o][n64] swizzled
  const int tid = threadIdx.x, lane = tid & 63, wv = tid >> 6;
  const int l15 = lane & 15, q = lane >> 4;
  const int wm = wv >> 1, wn = wv & 1;
  const int b = blockIdx.y, m0 = blockIdx.x * 64;
  const int srow = tid >> 3, sc = tid & 7;  // staging: row-in-32, 16B chunk

  f32x4 acc[2][4];
#pragma unroll
  for (int i = 0; i < 2; ++i)
#pragma unroll
    for (int j = 0; j < 4; ++j) acc[i][j] = (f32x4){0.f, 0.f, 0.f, 0.f};

  for (int ch = 0; ch < 24; ++ch) {
    const int e = ch >> 3, kt = ch & 7;
    const size_t arow0 = (size_t)(e * 64 + b) * 512 + m0;
    const size_t sbase = (size_t)(e * 64 + b) * 65536;
    __syncthreads();  // previous chunk's LDS reads done before restage
    if (LAYER == 1) {
#pragma unroll
      for (int is = 0; is < 2; ++is) {
        int row = is * 32 + srow;
        size_t gi = (arow0 + row) * 512 + kt * 64 + sc * 8;
        float4 v0 = *(const float4*)(adjf + gi);
        float4 v1 = *(const float4*)(adjf + gi + 4);
        u16x8 u = cvt8(v0, v1);
        *(u16x8*)(adjb + gi) = u;  // coalesced bf16 copy for layer 2
        int p = sc ^ (row & 7);
        *(u16x8*)(&As[row * 64 + p * 8]) = u;
      }
    } else {
#pragma unroll
      for (int is = 0; is < 2; ++is) {
        int row = is * 32 + srow;
        int gc = sc ^ (row & 7);
        gl_lds16(adjb + (arow0 + row) * 512 + kt * 64 + gc * 8,
                 &As[is * 2048 + wv * 512]);
      }
    }
#pragma unroll
    for (int is = 0; is < 4; ++is) {
      int row = is * 32 + srow;
      int gc = sc ^ (row & 7);
      gl_lds16(sup + sbase + (size_t)row * 512 + kt * 64 + gc * 8,
               &Bs[is * 2048 + wv * 512]);
    }
    __syncthreads();  // drains vmcnt (global_load_lds) + lgkm (ds_write)
#pragma unroll
    for (int kh = 0; kh < 2; ++kh) {
      bf16x8 af[2], bfr[4];
#pragma unroll
      for (int mt = 0; mt < 2; ++mt) {
        int r = wm * 32 + mt * 16 + l15;
        int p = (kh * 4 + q) ^ (r & 7);
        af[mt] = *(const bf16x8*)(&As[r * 64 + p * 8]);
      }
#pragma unroll
      for (int ot = 0; ot < 4; ++ot) {
        int r = wn * 64 + ot * 16 + l15;
        int p = (kh * 4 + q) ^ (r & 7);
        bfr[ot] = *(const bf16x8*)(&Bs[r * 64 + p * 8]);
      }
#pragma unroll
      for (int mt = 0; mt < 2; ++mt)
#pragma unroll
        for (int ot = 0; ot < 4; ++ot)
          acc[mt][ot] = MFMA16(af[mt], bfr[ot], acc[mt][ot]);
    }
  }

  // Epilogue: relu + highway. C row=m (q*4+r), col=o (l15).
#pragma unroll
  for (int mt = 0; mt < 2; ++mt) {
#pragma unroll
    for (int ot = 0; ot < 4; ++ot) {
#pragma unroll
      for (int r = 0; r < 4; ++r) {
        int m = m0 + wm * 32 + mt * 16 + q * 4 + r;
        int o = wn * 64 + ot * 16 + l15;
        size_t ridx = (size_t)(m * 64 + b) * 128 + o;
        float agg = acc[mt][ot][r];
        agg = agg > 0.f ? agg : 0.f;
        float tv = tg[ridx];
        float xv = x[ridx];
        dst[ridx] = fmaf(agg, tv, xv * (1.f - tv));
      }
    }
  }
}

// ---------------------------------------------------------------------------
extern "C" void kernel_launch(void* const* d_in, const int* in_sizes, int n_in,
                              void* d_out, int out_size, void* d_ws, size_t ws_size,
                              hipStream_t stream) {
  const float* x   = (const float*)d_in[0];
  const float* adj = (const float*)d_in[1];
  const float* W1  = (const float*)d_in[2];
  const float* b1  = (const float*)d_in[3];
  const float* Wh1 = (const float*)d_in[4];
  const float* bh1 = (const float*)d_in[5];
  const float* W2  = (const float*)d_in[6];
  const float* b2  = (const float*)d_in[7];
  const float* Wh2 = (const float*)d_in[8];
  const float* bh2 = (const float*)d_in[9];
  float* out = (float*)d_out;

  char* ws = (char*)d_ws;
  unsigned short* adjb = (unsigned short*)ws;                // 100,663,296 B
  unsigned short* sup  = (unsigned short*)(ws + 100663296);  //  25,165,824 B
  float*          tg   = (float*)(ws + 125829120);           //  16,777,216 B
  unsigned short* wt   = (unsigned short*)(ws + 142606336);  //     262,144 B

  dim3 blk(256);

  k_prep<<<dim3(8), blk, 0, stream>>>(W1, Wh1, W2, Wh2, wt);

  // Layer 1 (h -> d_out); k_agg<1> also produces adjb (bf16 adj) for layer 2
  k_support<<<dim3(8, 64), blk, 0, stream>>>(x, wt, b1, bh1, sup, tg);
  k_agg<1><<<dim3(8, 64), blk, 0, stream>>>(adj, adjb, sup, tg, x, out);

  // Layer 2 (in-place on d_out)
  k_support<<<dim3(8, 64), blk, 0, stream>>>(out, wt + 65536, b2, bh2, sup, tg);
  k_agg<2><<<dim3(8, 64), blk, 0, stream>>>(adj, adjb, sup, tg, out, out);
}